// Round 1
// baseline (6411.416 us; speedup 1.0000x reference)
//
#include <hip/hip_runtime.h>

#define B_ 128
#define T_ 2048
#define H_ 128
#define NI_ 64
#define NO_ 64

typedef short s16x8 __attribute__((ext_vector_type(8)));
typedef float f32x4 __attribute__((ext_vector_type(4)));

__device__ __forceinline__ unsigned short f2bf(float f) {
  unsigned int u = __float_as_uint(f);
  u += 0x7fffu + ((u >> 16) & 1u);
  return (unsigned short)(u >> 16);
}
__device__ __forceinline__ f32x4 mfma16(s16x8 a, s16x8 b, f32x4 c) {
  return __builtin_amdgcn_mfma_f32_16x16x32_bf16(a, b, c, 0, 0, 0);
}
// load 8 consecutive f32 and convert to a bf16 fragment (k = +0..7)
__device__ __forceinline__ s16x8 load8(const float* p) {
  float4 a = *reinterpret_cast<const float4*>(p);
  float4 b = *reinterpret_cast<const float4*>(p + 4);
  s16x8 r;
  r[0] = (short)f2bf(a.x); r[1] = (short)f2bf(a.y);
  r[2] = (short)f2bf(a.z); r[3] = (short)f2bf(a.w);
  r[4] = (short)f2bf(b.x); r[5] = (short)f2bf(b.y);
  r[6] = (short)f2bf(b.z); r[7] = (short)f2bf(b.w);
  return r;
}

// One WG = 16 batch rows, 8 waves. Wave w owns y-columns [64w, 64w+64) of
// y[16 x 512] = h @ [W_rec ; W_comb]^T  (+ fused x-projection, + fused out-proj).
__global__ __launch_bounds__(512, 2) void gru_seq_kernel(
    const float* __restrict__ X, const float* __restrict__ h0,
    const float* __restrict__ W_ih, const float* __restrict__ W_hh,
    const float* __restrict__ b_ih, const float* __restrict__ b_hh,
    const float* __restrict__ W_rec, const float* __restrict__ W_out,
    const float* __restrict__ b_out,
    float* __restrict__ out, float* __restrict__ hidden)
{
  // chunk (prologue W_comb staging, bf16 [128][136]) aliases ybuf (loop, f32 [16][516])
  __shared__ __align__(16) char smem0[34816];
  __shared__ __align__(16) float xnbuf[16][132];
  __shared__ __align__(16) unsigned short hlds[2048];  // h bf16, fragment-major + swizzle

  auto chunk = reinterpret_cast<unsigned short (*)[136]>(smem0);
  auto ybuf  = reinterpret_cast<float (*)[516]>(smem0);

  const int tid = threadIdx.x;
  const int w   = tid >> 6;         // wave 0..7
  const int l15 = tid & 15;
  const int lg  = (tid >> 4) & 3;   // lane group 0..3
  const int r0  = blockIdx.x * 16;  // batch-row base

  // ---- prologue: Bm fragments B[k][n] = Mcomb[n][k], n = 64w+16nt+l15 ----
  s16x8 bm[4][4];  // [kt][nt]
  if (w < 2) {     // n < 128 -> W_rec rows, straight from global
    #pragma unroll
    for (int nt = 0; nt < 4; ++nt) {
      int n = 64 * w + 16 * nt + l15;
      #pragma unroll
      for (int kt = 0; kt < 4; ++kt)
        bm[kt][nt] = load8(&W_rec[(size_t)n * H_ + 32 * kt + 8 * lg]);
    }
  }
  // W_comb = W_hh @ W_rec, computed in 3 chunks of 128 rows (all waves help)
  for (int c = 0; c < 3; ++c) {
    s16x8 afr[4];
    int m0 = 128 * c + 16 * w;
    #pragma unroll
    for (int kt = 0; kt < 4; ++kt)
      afr[kt] = load8(&W_hh[(size_t)(m0 + l15) * H_ + 32 * kt + 8 * lg]);
    f32x4 D[8];
    #pragma unroll
    for (int nt = 0; nt < 8; ++nt) {
      D[nt] = (f32x4){0.f, 0.f, 0.f, 0.f};
      #pragma unroll
      for (int kt = 0; kt < 4; ++kt) {
        s16x8 bfr;
        int kb = 32 * kt + 8 * lg;
        int n = 16 * nt + l15;
        #pragma unroll
        for (int j = 0; j < 8; ++j)
          bfr[j] = (short)f2bf(W_rec[(size_t)(kb + j) * H_ + n]);
        D[nt] = mfma16(afr[kt], bfr, D[nt]);
      }
    }
    #pragma unroll
    for (int nt = 0; nt < 8; ++nt)
      #pragma unroll
      for (int r = 0; r < 4; ++r)
        chunk[16 * w + 4 * lg + r][16 * nt + l15] = f2bf(D[nt][r]);
    __syncthreads();
    if ((w >> 1) == c + 1) {  // waves 2+2c, 3+2c pick up their Bm slice
      int wl = w & 1;
      #pragma unroll
      for (int nt = 0; nt < 4; ++nt) {
        int cr = 64 * wl + 16 * nt + l15;
        #pragma unroll
        for (int kt = 0; kt < 4; ++kt)
          bm[kt][nt] = *reinterpret_cast<const s16x8*>(&chunk[cr][32 * kt + 8 * lg]);
      }
    }
    __syncthreads();
  }

  // W_ih fragments (waves 2..7 add x-projection into their y columns)
  s16x8 bw[2][4];
  if (w >= 2) {
    #pragma unroll
    for (int nt = 0; nt < 4; ++nt) {
      int g = 64 * (w - 2) + 16 * nt + l15;
      #pragma unroll
      for (int kt = 0; kt < 2; ++kt)
        bw[kt][nt] = load8(&W_ih[(size_t)g * NI_ + 32 * kt + 8 * lg]);
    }
  }
  // W_out fragments (waves 0..3, one 16-col tile each)
  s16x8 bo[4];
  float bout = 0.f;
  if (w < 4) {
    int o = 16 * w + l15;
    #pragma unroll
    for (int kt = 0; kt < 4; ++kt)
      bo[kt] = load8(&W_out[(size_t)o * H_ + 32 * kt + 8 * lg]);
    bout = b_out[o];
  }
  // column biases: hp cols none; r/z cols b_hh+b_ih merged; n cols split
  float bias[4], biasx[4];
  #pragma unroll
  for (int nt = 0; nt < 4; ++nt) {
    bias[nt] = 0.f; biasx[nt] = 0.f;
    if (w >= 2) {
      int g = 64 * w + 16 * nt + l15 - 128;
      bias[nt] = (w < 6) ? (b_hh[g] + b_ih[g]) : b_hh[g];
      if (w >= 6) biasx[nt] = b_ih[g];
    }
  }
  // h0 -> A fragments
  s16x8 ha[4];
  #pragma unroll
  for (int kt = 0; kt < 4; ++kt)
    ha[kt] = load8(&h0[(size_t)(r0 + l15) * H_ + 32 * kt + 8 * lg]);

  // X prefetch (t = 0)
  s16x8 xa[2];
  float4 xt[4];
  if (w >= 2) {
    const float* xp = &X[(size_t)(r0 + l15) * T_ * NI_];
    #pragma unroll
    for (int kt = 0; kt < 2; ++kt) {
      xt[2 * kt]     = *reinterpret_cast<const float4*>(xp + 32 * kt + 8 * lg);
      xt[2 * kt + 1] = *reinterpret_cast<const float4*>(xp + 32 * kt + 8 * lg + 4);
    }
    #pragma unroll
    for (int kt = 0; kt < 2; ++kt) {
      float4 a = xt[2 * kt], b = xt[2 * kt + 1];
      s16x8 v;
      v[0]=(short)f2bf(a.x); v[1]=(short)f2bf(a.y); v[2]=(short)f2bf(a.z); v[3]=(short)f2bf(a.w);
      v[4]=(short)f2bf(b.x); v[5]=(short)f2bf(b.y); v[6]=(short)f2bf(b.z); v[7]=(short)f2bf(b.w);
      xa[kt] = v;
    }
  }

  const int row_g = tid >> 5;        // gate-phase row 0..15
  const int j0 = (tid & 31) * 4;     // gate-phase col base
  char* hb = reinterpret_cast<char*>(hlds);

  #pragma unroll 1
  for (int t = 0; t < T_; ++t) {
    // issue X prefetch for t+1 (lands during compute)
    if (w >= 2 && t + 1 < T_) {
      const float* xp = &X[((size_t)(r0 + l15) * T_ + (t + 1)) * NI_];
      #pragma unroll
      for (int kt = 0; kt < 2; ++kt) {
        xt[2 * kt]     = *reinterpret_cast<const float4*>(xp + 32 * kt + 8 * lg);
        xt[2 * kt + 1] = *reinterpret_cast<const float4*>(xp + 32 * kt + 8 * lg + 4);
      }
    }
    // y = [hp | W_comb h] (+ bias, + fused xg for waves 2..5)
    f32x4 acc[4];
    #pragma unroll
    for (int nt = 0; nt < 4; ++nt)
      acc[nt] = (f32x4){bias[nt], bias[nt], bias[nt], bias[nt]};
    #pragma unroll
    for (int kt = 0; kt < 4; ++kt)
      #pragma unroll
      for (int nt = 0; nt < 4; ++nt)
        acc[nt] = mfma16(ha[kt], bm[kt][nt], acc[nt]);
    f32x4 accx[4];
    if (w >= 2) {
      if (w < 6) {
        #pragma unroll
        for (int kt = 0; kt < 2; ++kt)
          #pragma unroll
          for (int nt = 0; nt < 4; ++nt)
            acc[nt] = mfma16(xa[kt], bw[kt][nt], acc[nt]);
      } else {  // n-gate x-side kept separate (b_hh_n is scaled by r)
        #pragma unroll
        for (int nt = 0; nt < 4; ++nt)
          accx[nt] = (f32x4){biasx[nt], biasx[nt], biasx[nt], biasx[nt]};
        #pragma unroll
        for (int kt = 0; kt < 2; ++kt)
          #pragma unroll
          for (int nt = 0; nt < 4; ++nt)
            accx[nt] = mfma16(xa[kt], bw[kt][nt], accx[nt]);
      }
    }
    // out-projection for t-1 (ha currently = hidden[t-1])
    if (w < 4 && t > 0) {
      f32x4 ao = (f32x4){0.f, 0.f, 0.f, 0.f};
      #pragma unroll
      for (int kt = 0; kt < 4; ++kt)
        ao = mfma16(ha[kt], bo[kt], ao);
      #pragma unroll
      for (int r = 0; r < 4; ++r)
        out[((size_t)(r0 + 4 * lg + r) * T_ + (t - 1)) * NO_ + 16 * w + l15] = ao[r] + bout;
    }
    // exchange y via LDS (f32)
    #pragma unroll
    for (int nt = 0; nt < 4; ++nt)
      #pragma unroll
      for (int r = 0; r < 4; ++r)
        ybuf[4 * lg + r][64 * w + 16 * nt + l15] = acc[nt][r];
    if (w >= 6)
      #pragma unroll
      for (int nt = 0; nt < 4; ++nt)
        #pragma unroll
        for (int r = 0; r < 4; ++r)
          xnbuf[4 * lg + r][64 * (w - 6) + 16 * nt + l15] = accx[nt][r];
    __syncthreads();

    // gates: each lane does 4 h-dims of one row
    float4 vhp = *reinterpret_cast<const float4*>(&ybuf[row_g][j0]);
    float4 vr  = *reinterpret_cast<const float4*>(&ybuf[row_g][128 + j0]);
    float4 vz  = *reinterpret_cast<const float4*>(&ybuf[row_g][256 + j0]);
    float4 vnh = *reinterpret_cast<const float4*>(&ybuf[row_g][384 + j0]);
    float4 vnx = *reinterpret_cast<const float4*>(&xnbuf[row_g][j0]);
    float hp[4] = {vhp.x, vhp.y, vhp.z, vhp.w};
    float pr[4] = {vr.x, vr.y, vr.z, vr.w};
    float pz[4] = {vz.x, vz.y, vz.z, vz.w};
    float nh[4] = {vnh.x, vnh.y, vnh.z, vnh.w};
    float nx[4] = {vnx.x, vnx.y, vnx.z, vnx.w};
    float hn[4];
    #pragma unroll
    for (int q = 0; q < 4; ++q) {
      float rg = 1.f / (1.f + __expf(-pr[q]));
      float zg = 1.f / (1.f + __expf(-pz[q]));
      float a2 = nx[q] + rg * nh[q];
      float e2 = __expf(2.f * a2);
      float ng = (e2 - 1.f) / (e2 + 1.f);          // tanh
      hn[q] = (1.f - zg) * ng + zg * hp[q];
    }
    *reinterpret_cast<float4*>(&hidden[((size_t)(r0 + row_g) * T_ + t) * H_ + j0]) =
        make_float4(hn[0], hn[1], hn[2], hn[3]);
    // h -> LDS, fragment-major bf16 with bank swizzle
    {
      int ktj = j0 >> 5, lgj = (j0 >> 3) & 3, ej = j0 & 7;
      unsigned int idx = (unsigned)((ktj * 4 + lgj) * 256 + row_g * 16 + ej * 2);
      idx ^= ((idx >> 8) & 7u) << 4;
      unsigned int p0 = (unsigned)f2bf(hn[0]) | ((unsigned)f2bf(hn[1]) << 16);
      unsigned int p1 = (unsigned)f2bf(hn[2]) | ((unsigned)f2bf(hn[3]) << 16);
      *reinterpret_cast<uint2*>(hb + idx) = make_uint2(p0, p1);
    }
    __syncthreads();
    // reload h fragments (linear/coalesced + same swizzle)
    #pragma unroll
    for (int kt = 0; kt < 4; ++kt) {
      unsigned int idx = (unsigned)((kt * 4 + lg) * 256 + l15 * 16);
      idx ^= ((idx >> 8) & 7u) << 4;
      ha[kt] = *reinterpret_cast<const s16x8*>(hb + idx);
    }
    // convert the prefetched X for next step
    if (w >= 2 && t + 1 < T_) {
      #pragma unroll
      for (int kt = 0; kt < 2; ++kt) {
        float4 a = xt[2 * kt], b = xt[2 * kt + 1];
        s16x8 v;
        v[0]=(short)f2bf(a.x); v[1]=(short)f2bf(a.y); v[2]=(short)f2bf(a.z); v[3]=(short)f2bf(a.w);
        v[4]=(short)f2bf(b.x); v[5]=(short)f2bf(b.y); v[6]=(short)f2bf(b.z); v[7]=(short)f2bf(b.w);
        xa[kt] = v;
      }
    }
  }
  // final out-projection (t = T-1)
  if (w < 4) {
    f32x4 ao = (f32x4){0.f, 0.f, 0.f, 0.f};
    #pragma unroll
    for (int kt = 0; kt < 4; ++kt)
      ao = mfma16(ha[kt], bo[kt], ao);
    #pragma unroll
    for (int r = 0; r < 4; ++r)
      out[((size_t)(r0 + 4 * lg + r) * T_ + (T_ - 1)) * NO_ + 16 * w + l15] = ao[r] + bout;
  }
}

extern "C" void kernel_launch(void* const* d_in, const int* in_sizes, int n_in,
                              void* d_out, int out_size, void* d_ws, size_t ws_size,
                              hipStream_t stream) {
  const float* X     = (const float*)d_in[0];
  const float* h0    = (const float*)d_in[1];
  const float* W_ih  = (const float*)d_in[2];
  const float* W_hh  = (const float*)d_in[3];
  const float* b_ih  = (const float*)d_in[4];
  const float* b_hh  = (const float*)d_in[5];
  const float* W_rec = (const float*)d_in[6];
  const float* W_out = (const float*)d_in[7];
  const float* b_out = (const float*)d_in[8];
  float* out    = (float*)d_out;                       // [B,T,NO]
  float* hidden = out + (size_t)B_ * T_ * NO_;         // [B,T,H]
  gru_seq_kernel<<<dim3(8), dim3(512), 0, stream>>>(X, h0, W_ih, W_hh, b_ih, b_hh,
                                                    W_rec, W_out, b_out, out, hidden);
}